// Round 2
// baseline (683.386 us; speedup 1.0000x reference)
//
#include <hip/hip_runtime.h>
#include <hip/hip_bf16.h>
#include <cstdint>

// Problem dims (fixed by reference)
#define G_ 256
#define P_ 1024
#define D_ 128
#define K_ 16
#define H_ 32
#define N_ (G_ * P_)

// d_out layout (floats), in reference return order
constexpr size_t OFF_COARSE = 0;                               // [G*K, D] = 524288
constexpr size_t OFF_ASSIGN = (size_t)G_ * K_ * D_;            // 524288
constexpr size_t OFF_SEND   = OFF_ASSIGN + (size_t)N_ * K_;    // 4718592
constexpr size_t OFF_RECV   = OFF_SEND + (size_t)G_ * K_ * K_; // 4784128
constexpr size_t OFF_EDGE   = OFF_RECV + (size_t)G_ * K_ * K_; // 4849664

// ---------------------------------------------------------------------------
// Kernel 1: per-node MLP (relu(x@W1+b1) @ W2 + b2) + softmax -> assignments
// One thread per node. W1/W2 staged in LDS, read as broadcast float4 (b128).
// ---------------------------------------------------------------------------
__global__ __launch_bounds__(256) void mlp_assign_kernel(
    const float* __restrict__ x, const float* __restrict__ W1,
    const float* __restrict__ b1, const float* __restrict__ W2,
    const float* __restrict__ b2, float* __restrict__ assign_out)
{
    __shared__ float W1s[D_ * H_];   // 16 KB, [d][j] row-major
    __shared__ float W2s[H_ * K_];   // 2 KB,  [j][k] row-major
    __shared__ float b1s[H_];
    __shared__ float b2s[K_];

    const int tid = threadIdx.x;
    for (int i = tid; i < D_ * H_; i += 256) W1s[i] = W1[i];
    for (int i = tid; i < H_ * K_; i += 256) W2s[i] = W2[i];
    if (tid < H_) b1s[tid] = b1[tid];
    if (tid < K_) b2s[tid] = b2[tid];
    __syncthreads();

    const int n = blockIdx.x * 256 + tid;
    const float4* __restrict__ xr = (const float4*)(x + (size_t)n * D_);
    const float4* __restrict__ W1v = (const float4*)W1s;
    const float4* __restrict__ W2v = (const float4*)W2s;

    float h[H_];
#pragma unroll
    for (int j = 0; j < H_; ++j) h[j] = b1s[j];

    // MLP layer 1: h[j] += x[d] * W1[d][j], 16 d-values per outer iter
#pragma unroll 2
    for (int i = 0; i < 8; ++i) {
        float4 xq0 = xr[i * 4 + 0];
        float4 xq1 = xr[i * 4 + 1];
        float4 xq2 = xr[i * 4 + 2];
        float4 xq3 = xr[i * 4 + 3];
        float xs[16] = {xq0.x, xq0.y, xq0.z, xq0.w,
                        xq1.x, xq1.y, xq1.z, xq1.w,
                        xq2.x, xq2.y, xq2.z, xq2.w,
                        xq3.x, xq3.y, xq3.z, xq3.w};
#pragma unroll
        for (int dd = 0; dd < 16; ++dd) {
            const float xv = xs[dd];
            const int d = i * 16 + dd;
#pragma unroll
            for (int jq = 0; jq < H_ / 4; ++jq) {
                float4 w = W1v[d * (H_ / 4) + jq];  // broadcast LDS b128
                h[4 * jq + 0] = fmaf(xv, w.x, h[4 * jq + 0]);
                h[4 * jq + 1] = fmaf(xv, w.y, h[4 * jq + 1]);
                h[4 * jq + 2] = fmaf(xv, w.z, h[4 * jq + 2]);
                h[4 * jq + 3] = fmaf(xv, w.w, h[4 * jq + 3]);
            }
        }
    }

    // MLP layer 2 (relu fused): lg[k] = b2[k] + sum_j relu(h[j]) * W2[j][k]
    float lg[K_];
#pragma unroll
    for (int k = 0; k < K_; ++k) lg[k] = b2s[k];
#pragma unroll
    for (int j = 0; j < H_; ++j) {
        const float hj = fmaxf(h[j], 0.0f);
#pragma unroll
        for (int kq = 0; kq < K_ / 4; ++kq) {
            float4 w = W2v[j * (K_ / 4) + kq];
            lg[4 * kq + 0] = fmaf(hj, w.x, lg[4 * kq + 0]);
            lg[4 * kq + 1] = fmaf(hj, w.y, lg[4 * kq + 1]);
            lg[4 * kq + 2] = fmaf(hj, w.z, lg[4 * kq + 2]);
            lg[4 * kq + 3] = fmaf(hj, w.w, lg[4 * kq + 3]);
        }
    }

    // softmax over K
    float m = lg[0];
#pragma unroll
    for (int k = 1; k < K_; ++k) m = fmaxf(m, lg[k]);
    float e[K_];
    float s = 0.0f;
#pragma unroll
    for (int k = 0; k < K_; ++k) { e[k] = __expf(lg[k] - m); s += e[k]; }
    const float inv = 1.0f / s;

    float4* __restrict__ ar = (float4*)(assign_out + (size_t)n * K_);
#pragma unroll
    for (int kq = 0; kq < K_ / 4; ++kq)
        ar[kq] = make_float4(e[4 * kq + 0] * inv, e[4 * kq + 1] * inv,
                             e[4 * kq + 2] * inv, e[4 * kq + 3] * inv);
}

// ---------------------------------------------------------------------------
// Kernel 2 (v2): coarse[g][k][d] = sum_{n in g} assign[n][k] * x[n][d]
// One block per graph, 1024 threads. Chunks of 32 nodes staged in LDS
// (double-buffered, reg->LDS T14 staging: next-chunk global loads stay in
// flight under compute; exactly one __syncthreads per chunk, at which point
// only the just-written ds_writes are outstanding).
// Thread = (dq = tid&31 -> d quad, s = tid>>5 -> node slot). Each thread owns
// ALL 16 k's for its 4 d's of its one node per chunk: 1 ds_read_b128 (x) +
// 4 ds_read_b128 (a, broadcast) + 64 FMA. acc = float4[16] statically
// indexed -> registers, NO spill (R1's 530 MB scratch-write bug).
// Final: exact k-loop LDS reduction over the 32 node-slots.
// ---------------------------------------------------------------------------
#define FMA4(dst, v, sc)                                                      \
    dst.x = fmaf(v.x, sc, dst.x); dst.y = fmaf(v.y, sc, dst.y);               \
    dst.z = fmaf(v.z, sc, dst.z); dst.w = fmaf(v.w, sc, dst.w)

__global__ __launch_bounds__(1024, 4) void coarse_kernel(
    const float* __restrict__ x, const float* __restrict__ assign,
    const int* __restrict__ n_node, float* __restrict__ coarse)
{
    __shared__ float xs[2][32 * 128];   // 2 x 16 KB node-feature chunks
    __shared__ float as_[2][32 * 16];   // 2 x 2 KB assignment chunks
    __shared__ int pref[G_];

    const int tid = threadIdx.x;

    // inclusive prefix scan of n_node (redundant per block; no workspace)
    if (tid < G_) pref[tid] = n_node[tid];
    __syncthreads();
    for (int st = 1; st < G_; st <<= 1) {
        int v = 0;
        if (tid < G_ && tid >= st) v = pref[tid - st];
        __syncthreads();
        if (tid < G_ && tid >= st) pref[tid] += v;
        __syncthreads();
    }
    const int g = blockIdx.x;
    const int start = (g == 0) ? 0 : min(pref[g - 1], N_);
    const int end   = (g == G_ - 1) ? N_ : min(pref[g], N_);

    const int dq = tid & 31;   // d = 4*dq .. 4*dq+3
    const int s  = tid >> 5;   // node slot within chunk, 0..31

    float4 acc[K_];
#pragma unroll
    for (int k = 0; k < K_; ++k) acc[k] = make_float4(0.f, 0.f, 0.f, 0.f);

    const int total = end - start;
    const int nfull = total >> 5;
    const int tail  = total & 31;

    float4 rx = make_float4(0.f, 0.f, 0.f, 0.f);
    float4 ra = make_float4(0.f, 0.f, 0.f, 0.f);
    if (nfull > 0) {
        rx = *(const float4*)(x + (size_t)start * D_ + tid * 4);
        if (tid < 128)
            ra = *(const float4*)(assign + (size_t)start * K_ + tid * 4);
    }

    int b = 0;
    for (int c = 0; c < nfull; ++c) {
        // write chunk c (compiler inserts counted vmcnt for rx/ra only)
        *(float4*)(&xs[b][tid * 4]) = rx;
        if (tid < 128) *(float4*)(&as_[b][tid * 4]) = ra;
        __syncthreads();  // nothing else outstanding -> cheap drain

        // issue chunk c+1 loads; in flight during compute below
        if (c + 1 < nfull) {
            const size_t nb = (size_t)start + (size_t)(c + 1) * 32;
            rx = *(const float4*)(x + nb * D_ + tid * 4);
            if (tid < 128)
                ra = *(const float4*)(assign + nb * K_ + tid * 4);
        }

        // compute chunk c: node = chunk_base + s, d = 4*dq..+3, all 16 k
        const float4 xv = *(const float4*)(&xs[b][s * D_ + dq * 4]);
        const float4* av = (const float4*)(&as_[b][s * K_]);
#pragma unroll
        for (int q = 0; q < 4; ++q) {
            const float4 a = av[q];
            FMA4(acc[4 * q + 0], xv, a.x);
            FMA4(acc[4 * q + 1], xv, a.y);
            FMA4(acc[4 * q + 2], xv, a.z);
            FMA4(acc[4 * q + 3], xv, a.w);
        }
        b ^= 1;
    }

    // tail (<32 nodes): direct-global, one node per slot s (never taken when
    // all graphs have a multiple-of-32 node count, as in this benchmark)
    if (tail > 0 && s < tail) {
        const size_t n = (size_t)start + (size_t)nfull * 32 + s;
        const float4 xv = *(const float4*)(x + n * D_ + dq * 4);
        const float4* av = (const float4*)(assign + n * K_);
#pragma unroll
        for (int q = 0; q < 4; ++q) {
            const float4 a = av[q];
            FMA4(acc[4 * q + 0], xv, a.x);
            FMA4(acc[4 * q + 1], xv, a.y);
            FMA4(acc[4 * q + 2], xv, a.z);
            FMA4(acc[4 * q + 3], xv, a.w);
        }
    }

    // exact reduction over the 32 node-slots, one k at a time through LDS
    __syncthreads();  // all compute done before reusing xs as scratch
    float* red = &xs[0][0];  // 32*128 floats = 16 KB
#pragma unroll 1
    for (int k = 0; k < K_; ++k) {
        *(float4*)(&red[s * D_ + dq * 4]) = acc[k];
        __syncthreads();
        if (tid < D_) {
            float sum = 0.f;
#pragma unroll
            for (int ss = 0; ss < 32; ++ss) sum += red[ss * D_ + tid];
            coarse[((size_t)g * K_ + k) * D_ + tid] = sum;
        }
        __syncthreads();
    }
}

// ---------------------------------------------------------------------------
// Kernel 3: fully-connected coarse edges per graph
// ---------------------------------------------------------------------------
__global__ __launch_bounds__(256) void edges_kernel(float* __restrict__ out)
{
    const int e = blockIdx.x * 256 + threadIdx.x;  // 0 .. G*K*K-1
    const int g = e >> 8;
    const int pair = e & 255;
    const int i = pair >> 4;
    const int j = pair & 15;
    out[OFF_SEND + e] = (float)(g * K_ + i);
    out[OFF_RECV + e] = (float)(g * K_ + j);
    out[OFF_EDGE + e] = 1.0f;
}

extern "C" void kernel_launch(void* const* d_in, const int* in_sizes, int n_in,
                              void* d_out, int out_size, void* d_ws, size_t ws_size,
                              hipStream_t stream)
{
    const float* x      = (const float*)d_in[0];
    const float* W1     = (const float*)d_in[1];
    const float* b1     = (const float*)d_in[2];
    const float* W2     = (const float*)d_in[3];
    const float* b2     = (const float*)d_in[4];
    const int*   n_node = (const int*)d_in[5];
    float* out = (float*)d_out;

    mlp_assign_kernel<<<N_ / 256, 256, 0, stream>>>(x, W1, b1, W2, b2, out + OFF_ASSIGN);
    coarse_kernel<<<G_, 1024, 0, stream>>>(x, out + OFF_ASSIGN, n_node, out + OFF_COARSE);
    edges_kernel<<<(G_ * K_ * K_) / 256, 256, 0, stream>>>(out);
}

// Round 3
// 86.110 us; speedup vs baseline: 7.9362x; 7.9362x over previous
//
#include <hip/hip_runtime.h>
#include <hip/hip_bf16.h>
#include <cstdint>

// Problem dims (fixed by reference)
#define G_ 256
#define P_ 1024
#define D_ 128
#define K_ 16
#define H_ 32
#define N_ (G_ * P_)

// d_out layout (floats), in reference return order
constexpr size_t OFF_COARSE = 0;                               // [G*K, D] = 524288
constexpr size_t OFF_ASSIGN = (size_t)G_ * K_ * D_;            // 524288
constexpr size_t OFF_SEND   = OFF_ASSIGN + (size_t)N_ * K_;    // 4718592
constexpr size_t OFF_RECV   = OFF_SEND + (size_t)G_ * K_ * K_; // 4784128
constexpr size_t OFF_EDGE   = OFF_RECV + (size_t)G_ * K_ * K_; // 4849664

// ---------------------------------------------------------------------------
// Kernel 1: per-node MLP (relu(x@W1+b1) @ W2 + b2) + softmax -> assignments
// One thread per node. W1/W2 staged in LDS, read as broadcast float4 (b128).
// ---------------------------------------------------------------------------
__global__ __launch_bounds__(256) void mlp_assign_kernel(
    const float* __restrict__ x, const float* __restrict__ W1,
    const float* __restrict__ b1, const float* __restrict__ W2,
    const float* __restrict__ b2, float* __restrict__ assign_out)
{
    __shared__ float W1s[D_ * H_];   // 16 KB, [d][j] row-major
    __shared__ float W2s[H_ * K_];   // 2 KB,  [j][k] row-major
    __shared__ float b1s[H_];
    __shared__ float b2s[K_];

    const int tid = threadIdx.x;
    for (int i = tid; i < D_ * H_; i += 256) W1s[i] = W1[i];
    for (int i = tid; i < H_ * K_; i += 256) W2s[i] = W2[i];
    if (tid < H_) b1s[tid] = b1[tid];
    if (tid < K_) b2s[tid] = b2[tid];
    __syncthreads();

    const int n = blockIdx.x * 256 + tid;
    const float4* __restrict__ xr = (const float4*)(x + (size_t)n * D_);
    const float4* __restrict__ W1v = (const float4*)W1s;
    const float4* __restrict__ W2v = (const float4*)W2s;

    float h[H_];
#pragma unroll
    for (int j = 0; j < H_; ++j) h[j] = b1s[j];

    // MLP layer 1: h[j] += x[d] * W1[d][j], 16 d-values per outer iter
#pragma unroll 2
    for (int i = 0; i < 8; ++i) {
        float4 xq0 = xr[i * 4 + 0];
        float4 xq1 = xr[i * 4 + 1];
        float4 xq2 = xr[i * 4 + 2];
        float4 xq3 = xr[i * 4 + 3];
        float xs[16] = {xq0.x, xq0.y, xq0.z, xq0.w,
                        xq1.x, xq1.y, xq1.z, xq1.w,
                        xq2.x, xq2.y, xq2.z, xq2.w,
                        xq3.x, xq3.y, xq3.z, xq3.w};
#pragma unroll
        for (int dd = 0; dd < 16; ++dd) {
            const float xv = xs[dd];
            const int d = i * 16 + dd;
#pragma unroll
            for (int jq = 0; jq < H_ / 4; ++jq) {
                float4 w = W1v[d * (H_ / 4) + jq];  // broadcast LDS b128
                h[4 * jq + 0] = fmaf(xv, w.x, h[4 * jq + 0]);
                h[4 * jq + 1] = fmaf(xv, w.y, h[4 * jq + 1]);
                h[4 * jq + 2] = fmaf(xv, w.z, h[4 * jq + 2]);
                h[4 * jq + 3] = fmaf(xv, w.w, h[4 * jq + 3]);
            }
        }
    }

    // MLP layer 2 (relu fused): lg[k] = b2[k] + sum_j relu(h[j]) * W2[j][k]
    float lg[K_];
#pragma unroll
    for (int k = 0; k < K_; ++k) lg[k] = b2s[k];
#pragma unroll
    for (int j = 0; j < H_; ++j) {
        const float hj = fmaxf(h[j], 0.0f);
#pragma unroll
        for (int kq = 0; kq < K_ / 4; ++kq) {
            float4 w = W2v[j * (K_ / 4) + kq];
            lg[4 * kq + 0] = fmaf(hj, w.x, lg[4 * kq + 0]);
            lg[4 * kq + 1] = fmaf(hj, w.y, lg[4 * kq + 1]);
            lg[4 * kq + 2] = fmaf(hj, w.z, lg[4 * kq + 2]);
            lg[4 * kq + 3] = fmaf(hj, w.w, lg[4 * kq + 3]);
        }
    }

    // softmax over K
    float m = lg[0];
#pragma unroll
    for (int k = 1; k < K_; ++k) m = fmaxf(m, lg[k]);
    float e[K_];
    float s = 0.0f;
#pragma unroll
    for (int k = 0; k < K_; ++k) { e[k] = __expf(lg[k] - m); s += e[k]; }
    const float inv = 1.0f / s;

    float4* __restrict__ ar = (float4*)(assign_out + (size_t)n * K_);
#pragma unroll
    for (int kq = 0; kq < K_ / 4; ++kq)
        ar[kq] = make_float4(e[4 * kq + 0] * inv, e[4 * kq + 1] * inv,
                             e[4 * kq + 2] * inv, e[4 * kq + 3] * inv);
}

// ---------------------------------------------------------------------------
// Kernel 2 (v3): coarse[g][k][d] = sum_{n in g} assign[n][k] * x[n][d]
// One block per graph, 1024 threads, 32-node LDS chunks, double-buffered
// reg->LDS staging. Thread = (dq = tid&31 -> d quad, s = tid>>5 -> node slot);
// each thread owns ALL 16 k's: 5 ds_read_b128 + 64 FMA per chunk.
// acc = float4[16] — EVERY access statically indexed (R2's runtime-indexed
// epilogue loop put acc in scratch: 2.16 GB of HBM writes. All loops over k
// touching acc are now fully unrolled).
// ---------------------------------------------------------------------------
#define FMA4(dst, v, sc)                                                      \
    dst.x = fmaf(v.x, sc, dst.x); dst.y = fmaf(v.y, sc, dst.y);               \
    dst.z = fmaf(v.z, sc, dst.z); dst.w = fmaf(v.w, sc, dst.w)

__global__ __launch_bounds__(1024, 4) void coarse_kernel(
    const float* __restrict__ x, const float* __restrict__ assign,
    const int* __restrict__ n_node, float* __restrict__ coarse)
{
    __shared__ float xs[2][32 * 128];   // 2 x 16 KB node-feature chunks
    __shared__ float as_[2][32 * 16];   // 2 x 2 KB assignment chunks
    __shared__ int pref[G_];

    const int tid = threadIdx.x;

    // inclusive prefix scan of n_node (redundant per block; no workspace)
    if (tid < G_) pref[tid] = n_node[tid];
    __syncthreads();
    for (int st = 1; st < G_; st <<= 1) {
        int v = 0;
        if (tid < G_ && tid >= st) v = pref[tid - st];
        __syncthreads();
        if (tid < G_ && tid >= st) pref[tid] += v;
        __syncthreads();
    }
    const int g = blockIdx.x;
    const int start = (g == 0) ? 0 : min(pref[g - 1], N_);
    const int end   = (g == G_ - 1) ? N_ : min(pref[g], N_);

    const int dq = tid & 31;   // d = 4*dq .. 4*dq+3
    const int s  = tid >> 5;   // node slot within chunk, 0..31

    float4 acc[K_];
#pragma unroll
    for (int k = 0; k < K_; ++k) acc[k] = make_float4(0.f, 0.f, 0.f, 0.f);

    const int total = end - start;
    const int nfull = total >> 5;
    const int tail  = total & 31;

    float4 rx = make_float4(0.f, 0.f, 0.f, 0.f);
    float4 ra = make_float4(0.f, 0.f, 0.f, 0.f);
    if (nfull > 0) {
        rx = *(const float4*)(x + (size_t)start * D_ + tid * 4);
        if (tid < 128)
            ra = *(const float4*)(assign + (size_t)start * K_ + tid * 4);
    }

    int b = 0;
    for (int c = 0; c < nfull; ++c) {
        // write chunk c (compiler inserts counted vmcnt for rx/ra only)
        *(float4*)(&xs[b][tid * 4]) = rx;
        if (tid < 128) *(float4*)(&as_[b][tid * 4]) = ra;
        __syncthreads();  // nothing else outstanding -> cheap drain

        // issue chunk c+1 loads; in flight during compute below
        if (c + 1 < nfull) {
            const size_t nb = (size_t)start + (size_t)(c + 1) * 32;
            rx = *(const float4*)(x + nb * D_ + tid * 4);
            if (tid < 128)
                ra = *(const float4*)(assign + nb * K_ + tid * 4);
        }

        // compute chunk c: node = chunk_base + s, d = 4*dq..+3, all 16 k
        const float4 xv = *(const float4*)(&xs[b][s * D_ + dq * 4]);
        const float4* av = (const float4*)(&as_[b][s * K_]);
#pragma unroll
        for (int q = 0; q < 4; ++q) {
            const float4 a = av[q];
            FMA4(acc[4 * q + 0], xv, a.x);
            FMA4(acc[4 * q + 1], xv, a.y);
            FMA4(acc[4 * q + 2], xv, a.z);
            FMA4(acc[4 * q + 3], xv, a.w);
        }
        b ^= 1;
    }

    // tail (<32 nodes): direct-global, one node per slot s (never taken when
    // all graphs have a multiple-of-32 node count, as in this benchmark)
    if (tail > 0 && s < tail) {
        const size_t n = (size_t)start + (size_t)nfull * 32 + s;
        const float4 xv = *(const float4*)(x + n * D_ + dq * 4);
        const float4* av = (const float4*)(assign + n * K_);
#pragma unroll
        for (int q = 0; q < 4; ++q) {
            const float4 a = av[q];
            FMA4(acc[4 * q + 0], xv, a.x);
            FMA4(acc[4 * q + 1], xv, a.y);
            FMA4(acc[4 * q + 2], xv, a.z);
            FMA4(acc[4 * q + 3], xv, a.w);
        }
    }

    // exact reduction over the 32 node-slots, one k at a time through LDS.
    // FULLY UNROLLED so acc[k] is a static index (registers, not scratch).
    __syncthreads();  // all compute done before reusing xs as scratch
    float* red = &xs[0][0];  // 32*128 floats = 16 KB
#pragma unroll
    for (int k = 0; k < K_; ++k) {
        *(float4*)(&red[s * D_ + dq * 4]) = acc[k];
        __syncthreads();
        if (tid < D_) {
            float sum = 0.f;
#pragma unroll
            for (int ss = 0; ss < 32; ++ss) sum += red[ss * D_ + tid];
            coarse[((size_t)g * K_ + k) * D_ + tid] = sum;
        }
        __syncthreads();
    }
}

// ---------------------------------------------------------------------------
// Kernel 3: fully-connected coarse edges per graph
// ---------------------------------------------------------------------------
__global__ __launch_bounds__(256) void edges_kernel(float* __restrict__ out)
{
    const int e = blockIdx.x * 256 + threadIdx.x;  // 0 .. G*K*K-1
    const int g = e >> 8;
    const int pair = e & 255;
    const int i = pair >> 4;
    const int j = pair & 15;
    out[OFF_SEND + e] = (float)(g * K_ + i);
    out[OFF_RECV + e] = (float)(g * K_ + j);
    out[OFF_EDGE + e] = 1.0f;
}

extern "C" void kernel_launch(void* const* d_in, const int* in_sizes, int n_in,
                              void* d_out, int out_size, void* d_ws, size_t ws_size,
                              hipStream_t stream)
{
    const float* x      = (const float*)d_in[0];
    const float* W1     = (const float*)d_in[1];
    const float* b1     = (const float*)d_in[2];
    const float* W2     = (const float*)d_in[3];
    const float* b2     = (const float*)d_in[4];
    const int*   n_node = (const int*)d_in[5];
    float* out = (float*)d_out;

    mlp_assign_kernel<<<N_ / 256, 256, 0, stream>>>(x, W1, b1, W2, b2, out + OFF_ASSIGN);
    coarse_kernel<<<G_, 1024, 0, stream>>>(x, out + OFF_ASSIGN, n_node, out + OFF_COARSE);
    edges_kernel<<<(G_ * K_ * K_) / 256, 256, 0, stream>>>(out);
}